// Round 3
// baseline (37.802 us; speedup 1.0000x reference)
//
#include <hip/hip_runtime.h>
#include <hip/hip_bf16.h>
#include <cstdint>
#include <cstddef>

// Problem constants (from reference)
#define NN     50000   // nodes
#define FIN    128
#define FOUT   128
#define FLIN   64
#define BM     64      // rows per block

typedef __attribute__((ext_vector_type(4))) float f32x4;
typedef __attribute__((ext_vector_type(8))) short s16x8;

// Saturating-limit fast sigmoid/tanh: NaN-free at +/-inf, no clamps needed.
__device__ __forceinline__ float fsigmoid(float x) {
    return __builtin_amdgcn_rcpf(1.f + __builtin_amdgcn_exp2f(-1.4426950408889634f * x));
}
__device__ __forceinline__ float ftanh(float x) {
    return 1.f - 2.f * __builtin_amdgcn_rcpf(1.f + __builtin_amdgcn_exp2f(2.8853900817779268f * x));
}

// Pack 8 floats -> bf16 fragment via v_cvt_pk_bf16_f32 (RNE), 4 instrs.
__device__ __forceinline__ s16x8 pack_frag(const float f[8]) {
    union { unsigned int u[4]; s16x8 v; } r;
    __hip_bfloat162 p0 = __float22bfloat162_rn(make_float2(f[0], f[1]));
    __hip_bfloat162 p1 = __float22bfloat162_rn(make_float2(f[2], f[3]));
    __hip_bfloat162 p2 = __float22bfloat162_rn(make_float2(f[4], f[5]));
    __hip_bfloat162 p3 = __float22bfloat162_rn(make_float2(f[6], f[7]));
    r.u[0] = *(unsigned int*)&p0;
    r.u[1] = *(unsigned int*)&p1;
    r.u[2] = *(unsigned int*)&p2;
    r.u[3] = *(unsigned int*)&p3;
    return r.v;
}

// Gather one B fragment (16x16x32 bf16 layout) straight from a row-major
// (K x Ncols) f32 weight matrix: lane holds W[kb*32 + (lane>>4)*8 + i][col],
// i = 0..7, col = ct*16 + (lane&15). The 8 loads are base + i*stride, folded
// into offset immediates; per instruction the wave touches 4 rows x 64
// contiguous bytes (all fetched lines fully used).
__device__ __forceinline__ s16x8 gather_bfrag(const float* __restrict__ W,
                                              int ncols, int kb, int ct,
                                              int lg, int lc) {
    const float* p = W + (size_t)(kb * 32 + lg * 8) * ncols + ct * 16 + lc;
    float f[8];
    #pragma unroll
    for (int i = 0; i < 8; ++i) f[i] = p[(size_t)i * ncols];
    return pack_frag(f);
}

// ---------------------------------------------------------------------------
// Single fused kernel: 64 rows / block, 512 threads (8 waves = 2 row x 4 col).
// Phase 1: G = x_tile @ [Wx_i | Wx_c | Wx_o]  (bf16 MFMA, K=128, N=384)
//   weights gathered directly from natural layout (L2-warm), no pack kernel.
// Epilogue 1: LSTM cell from zero state, h = relu(O * tanh(C)) -> LDS bf16.
// Phase 2: out = h_tile @ lin_W + lin_b  (K=128, N=64), store f32.
// ---------------------------------------------------------------------------
__global__ __launch_bounds__(512) void gclstm_fused(
    const float* __restrict__ x,
    const float* __restrict__ Wx,               // (4,128,128)
    const float* __restrict__ b_gate,           // (4,1,128)
    const float* __restrict__ w_c,              // (3,1,128)
    const float* __restrict__ cheb_b,           // (4,128)
    const float* __restrict__ lin_W,            // (128,64)
    const float* __restrict__ lin_b,            // (64)
    float* __restrict__ out)                    // (NN,64)
{
    __shared__ __align__(16) unsigned char ldsx[BM * 256];  // 64 rows x 128 bf16, swizzled
    __shared__ __align__(16) unsigned char ldsh[BM * 256];

    const int tid  = threadIdx.x;
    const int w    = tid >> 6;       // wave 0..7
    const int wr   = w >> 2;         // row group (0..1)
    const int wc   = w & 3;          // col group (0..3): per-gate col tiles {2wc, 2wc+1}
    const int lane = tid & 63;
    const int lg   = lane >> 4;      // 0..3
    const int lc   = lane & 15;
    const long m0  = (long)blockIdx.x * BM;

    // ---- stage x tile -> LDS bf16, XOR-swizzled ----
    #pragma unroll
    for (int it = 0; it < 4; ++it) {
        int idx = tid + it * 512;    // float4 index: row = idx/32, c4 = idx%32
        int row = idx >> 5;
        int c4  = idx & 31;
        f32x4 v = {0.f, 0.f, 0.f, 0.f};
        if (m0 + row < NN)
            v = *(const f32x4*)(x + (m0 + row) * FIN + c4 * 4);
        __hip_bfloat162 p01 = __float22bfloat162_rn(make_float2(v.x, v.y));
        __hip_bfloat162 p23 = __float22bfloat162_rn(make_float2(v.z, v.w));
        int byte = (row * 256 + c4 * 8) ^ ((row & 7) << 4);
        *(uint2*)(ldsx + byte) = make_uint2(*(unsigned*)&p01, *(unsigned*)&p23);
    }
    __syncthreads();

    // ---- phase 1 A fragments: rows wr*32 + rt*16 + lc, k = kb*32 + lg*8 + i ----
    s16x8 afr[2][4];
    #pragma unroll
    for (int rt = 0; rt < 2; ++rt)
        #pragma unroll
        for (int kb = 0; kb < 4; ++kb) {
            int row  = wr * 32 + rt * 16 + lc;
            int byte = (row * 256 + kb * 64 + lg * 16) ^ ((row & 7) << 4);
            afr[rt][kb] = *(const s16x8*)(ldsx + byte);
        }

    f32x4 acc[2][3][2];
    #pragma unroll
    for (int rt = 0; rt < 2; ++rt)
        #pragma unroll
        for (int gg = 0; gg < 3; ++gg)
            #pragma unroll
            for (int c2 = 0; c2 < 2; ++c2)
                acc[rt][gg][c2] = (f32x4){0.f, 0.f, 0.f, 0.f};

    // gate index map gg -> {i, c, o} = Wx[{0, 2, 3}]
    #pragma unroll
    for (int gg = 0; gg < 3; ++gg) {
        const int g = (gg == 0) ? 0 : (gg == 1 ? 2 : 3);
        const float* Wg = Wx + (size_t)g * (FIN * FOUT);
        #pragma unroll
        for (int c2 = 0; c2 < 2; ++c2) {
            int ct = 2 * wc + c2;
            s16x8 b0 = gather_bfrag(Wg, FOUT, 0, ct, lg, lc);
            s16x8 b1 = gather_bfrag(Wg, FOUT, 1, ct, lg, lc);
            s16x8 b2 = gather_bfrag(Wg, FOUT, 2, ct, lg, lc);
            s16x8 b3 = gather_bfrag(Wg, FOUT, 3, ct, lg, lc);
            #pragma unroll
            for (int rt = 0; rt < 2; ++rt) {
                acc[rt][gg][c2] = __builtin_amdgcn_mfma_f32_16x16x32_bf16(afr[rt][0], b0, acc[rt][gg][c2], 0, 0, 0);
                acc[rt][gg][c2] = __builtin_amdgcn_mfma_f32_16x16x32_bf16(afr[rt][1], b1, acc[rt][gg][c2], 0, 0, 0);
                acc[rt][gg][c2] = __builtin_amdgcn_mfma_f32_16x16x32_bf16(afr[rt][2], b2, acc[rt][gg][c2], 0, 0, 0);
                acc[rt][gg][c2] = __builtin_amdgcn_mfma_f32_16x16x32_bf16(afr[rt][3], b3, acc[rt][gg][c2], 0, 0, 0);
            }
        }
    }

    // ---- epilogue 1: LSTM cell (H=C=0 initial state), h -> LDS bf16 ----
    #pragma unroll
    for (int c2 = 0; c2 < 2; ++c2) {
        int col = (2 * wc + c2) * 16 + lc;         // 0..127
        float bi  = cheb_b[0 * 128 + col] + b_gate[0 * 128 + col];
        float bc  = cheb_b[2 * 128 + col] + b_gate[2 * 128 + col];
        float bo  = cheb_b[3 * 128 + col] + b_gate[3 * 128 + col];
        float wco = w_c[2 * 128 + col];
        #pragma unroll
        for (int rt = 0; rt < 2; ++rt) {
            #pragma unroll
            for (int r = 0; r < 4; ++r) {
                float I = fsigmoid(acc[rt][0][c2][r] + bi);
                float T = ftanh(acc[rt][1][c2][r] + bc);
                float C = I * T;
                float O = fsigmoid(acc[rt][2][c2][r] + wco * C + bo);
                float h = fmaxf(O * ftanh(C), 0.f);
                int row  = wr * 32 + rt * 16 + lg * 4 + r;
                int byte = (row * 256 + col * 2) ^ ((row & 7) << 4);
                *(unsigned short*)(ldsh + byte) = __bfloat16_as_ushort(__float2bfloat16(h));
            }
        }
    }
    __syncthreads();

    // ---- phase 2: out = h @ lin_W + lin_b; wave w: row tile w>>1, col tiles {(w&1)*2,+1} ----
    const int rt2 = w >> 1;                // 0..3
    const int ct0 = (w & 1) * 2;           // 0 or 2
    s16x8 ha[4];
    #pragma unroll
    for (int kb = 0; kb < 4; ++kb) {
        int row  = rt2 * 16 + lc;
        int byte = (row * 256 + kb * 64 + lg * 16) ^ ((row & 7) << 4);
        ha[kb] = *(const s16x8*)(ldsh + byte);
    }
    f32x4 acc2[2];
    #pragma unroll
    for (int c2 = 0; c2 < 2; ++c2) {
        acc2[c2] = (f32x4){0.f, 0.f, 0.f, 0.f};
        int ct = ct0 + c2;
        s16x8 l0 = gather_bfrag(lin_W, FLIN, 0, ct, lg, lc);
        s16x8 l1 = gather_bfrag(lin_W, FLIN, 1, ct, lg, lc);
        s16x8 l2 = gather_bfrag(lin_W, FLIN, 2, ct, lg, lc);
        s16x8 l3 = gather_bfrag(lin_W, FLIN, 3, ct, lg, lc);
        acc2[c2] = __builtin_amdgcn_mfma_f32_16x16x32_bf16(ha[0], l0, acc2[c2], 0, 0, 0);
        acc2[c2] = __builtin_amdgcn_mfma_f32_16x16x32_bf16(ha[1], l1, acc2[c2], 0, 0, 0);
        acc2[c2] = __builtin_amdgcn_mfma_f32_16x16x32_bf16(ha[2], l2, acc2[c2], 0, 0, 0);
        acc2[c2] = __builtin_amdgcn_mfma_f32_16x16x32_bf16(ha[3], l3, acc2[c2], 0, 0, 0);
    }
    #pragma unroll
    for (int c2 = 0; c2 < 2; ++c2) {
        int col  = (ct0 + c2) * 16 + lc;
        float lb = lin_b[col];
        #pragma unroll
        for (int r = 0; r < 4; ++r) {
            long row = m0 + rt2 * 16 + lg * 4 + r;
            if (row < NN)
                out[row * FLIN + col] = acc2[c2][r] + lb;
        }
    }
}

extern "C" void kernel_launch(void* const* d_in, const int* in_sizes, int n_in,
                              void* d_out, int out_size, void* d_ws, size_t ws_size,
                              hipStream_t stream) {
    const float* x      = (const float*)d_in[0];
    // d_in[1] edge_index, d_in[2] edge_weight, d_in[6] cheb_W: dead (H=C=0)
    const float* Wx     = (const float*)d_in[3];
    const float* b_gate = (const float*)d_in[4];
    const float* w_c    = (const float*)d_in[5];
    const float* cheb_b = (const float*)d_in[7];
    const float* lin_W  = (const float*)d_in[8];
    const float* lin_b  = (const float*)d_in[9];
    float* out          = (float*)d_out;

    int grid = (NN + BM - 1) / BM;   // 782
    gclstm_fused<<<grid, 512, 0, stream>>>(x, Wx, b_gate, w_c, cheb_b, lin_W, lin_b, out);
}

// Round 4
// 28.929 us; speedup vs baseline: 1.3067x; 1.3067x over previous
//
#include <hip/hip_runtime.h>
#include <hip/hip_bf16.h>
#include <cstdint>
#include <cstddef>

// Problem constants (from reference)
#define NN     50000   // nodes
#define FIN    128
#define FOUT   128
#define FLIN   64
#define BM     32      // rows per tile
#define NT     1563    // ceil(NN/BM)
#define GRID   512     // persistent blocks, 2 per CU

typedef __attribute__((ext_vector_type(4))) float f32x4;
typedef __attribute__((ext_vector_type(8))) short s16x8;

// Saturating-limit fast sigmoid/tanh: NaN-free at +/-inf, no clamps needed.
__device__ __forceinline__ float fsigmoid(float x) {
    return __builtin_amdgcn_rcpf(1.f + __builtin_amdgcn_exp2f(-1.4426950408889634f * x));
}
__device__ __forceinline__ float ftanh(float x) {
    return 1.f - 2.f * __builtin_amdgcn_rcpf(1.f + __builtin_amdgcn_exp2f(2.8853900817779268f * x));
}

// Pack 8 floats -> bf16 fragment via v_cvt_pk_bf16_f32 (RNE).
__device__ __forceinline__ s16x8 pack_frag(const float f[8]) {
    union { unsigned int u[4]; s16x8 v; } r;
    __hip_bfloat162 p0 = __float22bfloat162_rn(make_float2(f[0], f[1]));
    __hip_bfloat162 p1 = __float22bfloat162_rn(make_float2(f[2], f[3]));
    __hip_bfloat162 p2 = __float22bfloat162_rn(make_float2(f[4], f[5]));
    __hip_bfloat162 p3 = __float22bfloat162_rn(make_float2(f[6], f[7]));
    r.u[0] = *(unsigned int*)&p0;
    r.u[1] = *(unsigned int*)&p1;
    r.u[2] = *(unsigned int*)&p2;
    r.u[3] = *(unsigned int*)&p3;
    return r.v;
}

// Gather one B fragment (16x16x32 bf16 layout) from row-major (K x ncols) f32:
// lane holds W[kb*32 + lg*8 + i][ct*16 + lc], i = 0..7.
__device__ __forceinline__ s16x8 gather_bfrag(const float* __restrict__ W,
                                              int ncols, int kb, int ct,
                                              int lg, int lc) {
    const float* p = W + (size_t)(kb * 32 + lg * 8) * ncols + ct * 16 + lc;
    float f[8];
    #pragma unroll
    for (int i = 0; i < 8; ++i) f[i] = p[(size_t)i * ncols];
    return pack_frag(f);
}

// ---------------------------------------------------------------------------
// Persistent fused kernel: 512 blocks x 256 threads (4 waves, each wave owns
// 2 col-tiles of every gate). Per block: gate B-frags -> registers ONCE,
// lin_W frags -> LDS ONCE, then loop over row tiles (stride GRID) with
// double-buffered x staging (prefetch next tile during current compute).
// ---------------------------------------------------------------------------
__global__ __launch_bounds__(256, 2) void gclstm_fused(
    const float* __restrict__ x,
    const float* __restrict__ Wx,               // (4,128,128)
    const float* __restrict__ b_gate,           // (4,1,128)
    const float* __restrict__ w_c,              // (3,1,128)
    const float* __restrict__ cheb_b,           // (4,128)
    const float* __restrict__ lin_W,            // (128,64)
    const float* __restrict__ lin_b,            // (64)
    float* __restrict__ out)                    // (NN,64)
{
    __shared__ __align__(16) unsigned char ldsx[2][BM * 256];   // 2 x 8KB, swizzled bf16
    __shared__ __align__(16) unsigned char ldsh[BM * 256];      // 8KB
    __shared__ __align__(16) unsigned char ldsw[16 * 64 * 16];  // 16KB lin frags

    const int tid  = threadIdx.x;
    const int w    = tid >> 6;       // wave 0..3 = col group
    const int lane = tid & 63;
    const int lg   = lane >> 4;      // 0..3
    const int lc   = lane & 15;

    // ---- prologue A: gate B fragments -> registers (once per block) ----
    // gg -> gates {i, c, o} = Wx[{0, 2, 3}]
    s16x8 bfr[3][2][4];
    #pragma unroll
    for (int gg = 0; gg < 3; ++gg) {
        const int g = (gg == 0) ? 0 : (gg == 1 ? 2 : 3);
        const float* Wg = Wx + (size_t)g * (FIN * FOUT);
        #pragma unroll
        for (int c2 = 0; c2 < 2; ++c2)
            #pragma unroll
            for (int kb = 0; kb < 4; ++kb)
                bfr[gg][c2][kb] = gather_bfrag(Wg, FOUT, kb, 2 * w + c2, lg, lc);
    }

    // ---- prologue B: lin_W fragments -> LDS (once per block) ----
    #pragma unroll
    for (int it = 0; it < 4; ++it) {
        int fi = w + it * 4;          // 0..15: ct = fi>>2, kb = fi&3
        s16x8 f = gather_bfrag(lin_W, FLIN, fi & 3, fi >> 2, lg, lc);
        *(s16x8*)(ldsw + ((size_t)fi * 64 + lane) * 16) = f;
    }

    // ---- prologue C: per-thread bias scalars ----
    float bi[2], bc[2], bo[2], wco[2], lb[2];
    #pragma unroll
    for (int c2 = 0; c2 < 2; ++c2) {
        int col = (2 * w + c2) * 16 + lc;
        bi[c2]  = cheb_b[0 * 128 + col] + b_gate[0 * 128 + col];
        bc[c2]  = cheb_b[2 * 128 + col] + b_gate[2 * 128 + col];
        bo[c2]  = cheb_b[3 * 128 + col] + b_gate[3 * 128 + col];
        wco[c2] = w_c[2 * 128 + col];
        int colL = ((w & 1) * 2 + c2) * 16 + lc;   // phase-2 col
        lb[c2]  = lin_b[colL];
    }

    // ---- stage first tile ----
    int t = blockIdx.x;
    {
        long m0 = (long)t * BM;
        #pragma unroll
        for (int it = 0; it < 4; ++it) {
            int idx = tid + it * 256;    // f32x4 slot: row = idx/32, c4 = idx%32
            int row = idx >> 5;
            int c4  = idx & 31;
            f32x4 v = {0.f, 0.f, 0.f, 0.f};
            if (m0 + row < NN) v = *(const f32x4*)(x + (m0 + row) * FIN + c4 * 4);
            __hip_bfloat162 p01 = __float22bfloat162_rn(make_float2(v.x, v.y));
            __hip_bfloat162 p23 = __float22bfloat162_rn(make_float2(v.z, v.w));
            int byte = (row * 256 + c4 * 8) ^ ((row & 7) << 4);
            *(uint2*)(ldsx[0] + byte) = make_uint2(*(unsigned*)&p01, *(unsigned*)&p23);
        }
    }
    __syncthreads();

    int buf = 0;
    while (t < NT) {
        const int tn = t + GRID;
        const bool havenext = (tn < NT);

        // ---- issue next tile's global loads (overlap with phase 1) ----
        f32x4 xn[4];
        int nrow[4], nc4[4];
        if (havenext) {
            long m0n = (long)tn * BM;
            #pragma unroll
            for (int it = 0; it < 4; ++it) {
                int idx  = tid + it * 256;
                nrow[it] = idx >> 5;
                nc4[it]  = idx & 31;
                xn[it] = (f32x4){0.f, 0.f, 0.f, 0.f};
                if (m0n + nrow[it] < NN)
                    xn[it] = *(const f32x4*)(x + (m0n + nrow[it]) * FIN + nc4[it] * 4);
            }
        }

        // ---- phase 1: A fragments from ldsx[buf] ----
        s16x8 afr[2][4];
        #pragma unroll
        for (int rt = 0; rt < 2; ++rt)
            #pragma unroll
            for (int kb = 0; kb < 4; ++kb) {
                int row  = rt * 16 + lc;
                int byte = (row * 256 + kb * 64 + lg * 16) ^ ((row & 7) << 4);
                afr[rt][kb] = *(const s16x8*)(ldsx[buf] + byte);
            }

        f32x4 acc[2][3][2];
        #pragma unroll
        for (int rt = 0; rt < 2; ++rt)
            #pragma unroll
            for (int gg = 0; gg < 3; ++gg)
                #pragma unroll
                for (int c2 = 0; c2 < 2; ++c2)
                    acc[rt][gg][c2] = (f32x4){0.f, 0.f, 0.f, 0.f};

        #pragma unroll
        for (int gg = 0; gg < 3; ++gg)
            #pragma unroll
            for (int c2 = 0; c2 < 2; ++c2)
                #pragma unroll
                for (int rt = 0; rt < 2; ++rt)
                    #pragma unroll
                    for (int kb = 0; kb < 4; ++kb)
                        acc[rt][gg][c2] = __builtin_amdgcn_mfma_f32_16x16x32_bf16(
                            afr[rt][kb], bfr[gg][c2][kb], acc[rt][gg][c2], 0, 0, 0);

        // ---- epilogue 1: LSTM cell (H=C=0), h -> ldsh ----
        #pragma unroll
        for (int c2 = 0; c2 < 2; ++c2) {
            int col = (2 * w + c2) * 16 + lc;
            #pragma unroll
            for (int rt = 0; rt < 2; ++rt)
                #pragma unroll
                for (int r = 0; r < 4; ++r) {
                    float I = fsigmoid(acc[rt][0][c2][r] + bi[c2]);
                    float T = ftanh(acc[rt][1][c2][r] + bc[c2]);
                    float C = I * T;
                    float O = fsigmoid(acc[rt][2][c2][r] + wco[c2] * C + bo[c2]);
                    float h = fmaxf(O * ftanh(C), 0.f);
                    int row  = rt * 16 + lg * 4 + r;
                    int byte = (row * 256 + col * 2) ^ ((row & 7) << 4);
                    *(unsigned short*)(ldsh + byte) = __bfloat16_as_ushort(__float2bfloat16(h));
                }
        }
        __syncthreads();

        // ---- phase 2: out = h @ lin_W + lin_b ----
        const int rt2 = w >> 1;           // row tile 0..1
        const int ct0 = (w & 1) * 2;      // col tiles {ct0, ct0+1}
        s16x8 ha[4];
        #pragma unroll
        for (int kb = 0; kb < 4; ++kb) {
            int row  = rt2 * 16 + lc;
            int byte = (row * 256 + kb * 64 + lg * 16) ^ ((row & 7) << 4);
            ha[kb] = *(const s16x8*)(ldsh + byte);
        }
        f32x4 acc2[2];
        #pragma unroll
        for (int c2 = 0; c2 < 2; ++c2) {
            acc2[c2] = (f32x4){0.f, 0.f, 0.f, 0.f};
            int ct = ct0 + c2;
            #pragma unroll
            for (int kb = 0; kb < 4; ++kb) {
                s16x8 lf = *(const s16x8*)(ldsw + ((size_t)(ct * 4 + kb) * 64 + lane) * 16);
                acc2[c2] = __builtin_amdgcn_mfma_f32_16x16x32_bf16(ha[kb], lf, acc2[c2], 0, 0, 0);
            }
        }
        {
            long m0 = (long)t * BM;
            #pragma unroll
            for (int c2 = 0; c2 < 2; ++c2) {
                int col = (ct0 + c2) * 16 + lc;
                #pragma unroll
                for (int r = 0; r < 4; ++r) {
                    long row = m0 + rt2 * 16 + lg * 4 + r;
                    if (row < NN) out[row * FLIN + col] = acc2[c2][r] + lb[c2];
                }
            }
        }

        // ---- stage next tile into other buffer ----
        if (havenext) {
            #pragma unroll
            for (int it = 0; it < 4; ++it) {
                __hip_bfloat162 p01 = __float22bfloat162_rn(make_float2(xn[it].x, xn[it].y));
                __hip_bfloat162 p23 = __float22bfloat162_rn(make_float2(xn[it].z, xn[it].w));
                int byte = (nrow[it] * 256 + nc4[it] * 8) ^ ((nrow[it] & 7) << 4);
                *(uint2*)(ldsx[buf ^ 1] + byte) = make_uint2(*(unsigned*)&p01, *(unsigned*)&p23);
            }
        }
        __syncthreads();
        t = tn;
        buf ^= 1;
    }
}

extern "C" void kernel_launch(void* const* d_in, const int* in_sizes, int n_in,
                              void* d_out, int out_size, void* d_ws, size_t ws_size,
                              hipStream_t stream) {
    const float* x      = (const float*)d_in[0];
    // d_in[1] edge_index, d_in[2] edge_weight, d_in[6] cheb_W: dead (H=C=0)
    const float* Wx     = (const float*)d_in[3];
    const float* b_gate = (const float*)d_in[4];
    const float* w_c    = (const float*)d_in[5];
    const float* cheb_b = (const float*)d_in[7];
    const float* lin_W  = (const float*)d_in[8];
    const float* lin_b  = (const float*)d_in[9];
    float* out          = (float*)d_out;

    gclstm_fused<<<GRID, 256, 0, stream>>>(x, Wx, b_gate, w_c, cheb_b, lin_W, lin_b, out);
}